// Round 16
// baseline (134.061 us; speedup 1.0000x reference)
//
#include <hip/hip_runtime.h>

typedef _Float16 f16;
typedef _Float16 f16x8 __attribute__((ext_vector_type(8)));
typedef _Float16 f16x4 __attribute__((ext_vector_type(4)));
typedef float f32x4 __attribute__((ext_vector_type(4)));

__device__ __forceinline__ float rcpf(float x) { return __builtin_amdgcn_rcpf(x); }

// ---------------- kernel 1: weight convert -> FRAGMENT-ORDERED layout ------
// Wt'[(nt*3+w)*8+kt][kq][ni][rl][8 halfs]   (nt = 64-wide h tile, 0..7)
__global__ void __launch_bounds__(256) cvt_w(const float* __restrict__ Wr,
                                             const float* __restrict__ Wz,
                                             const float* __restrict__ Wh,
                                             f16* __restrict__ out) {
  int o = blockIdx.x * 256 + threadIdx.x;        // < 49152
  int rl = o & 15, ni = (o >> 4) & 3, kq = (o >> 6) & 3, kt = (o >> 8) & 7;
  int wnt = o >> 11;
  int w = wnt % 3, nt = wnt / 3;
  int n = nt * 64 + ni * 16 + rl;
  int k0 = kt * 32 + kq * 8;
  const float* W = (w == 0) ? Wr : ((w == 1) ? Wz : Wh);
  f16x8 v;
#pragma unroll
  for (int e = 0; e < 8; ++e) v[e] = (f16)W[(size_t)(k0 + e) * 512 + n];
  *(f16x8*)(out + (size_t)o * 8) = v;
}

// ---------------- kernel 2: x convert f32->f16, FRAGMENT-ORDERED -----------
// Xf'[m16*8+kt][kq][rl][8 halfs]
__global__ void __launch_bounds__(256) cvt_x(const float* __restrict__ in,
                                             f16* __restrict__ out) {
  int o = blockIdx.x * 256 + threadIdx.x;        // < 2097152
  int rl = o & 15, kq = (o >> 4) & 3, kt = (o >> 6) & 7, m16 = o >> 9;
  const float* src = in + (size_t)(m16 * 16 + rl) * 256 + kt * 32 + kq * 8;
  f16x8 v;
#pragma unroll
  for (int e = 0; e < 8; ++e) v[e] = (f16)src[e];
  *(f16x8*)(out + (size_t)o * 8) = v;
}

// ---------------- kernel 3: producer/consumer fused GEMM + scan ------------
// Block = (b, hs: 64-wide h slice), grid 1024 = 128b x 8hs, 256 thr = 4 waves.
// Waves 0..2 (producers): one WEIGHT each, tile 64t x 64h (acc[4][4]),
//   with kt-level even/odd REGISTER double-buffer: next kt's 8 loads issue
//   while current kt's 16 MFMAs run (hides the ~200cy L2 latency that paced
//   R10/R15 at ~1 MFMA/100cy/wave). Phase q -> LDS P buf q&1.
// Wave 3 (consumer): 64 chains, scans 64 t-steps of phase p from buf p&1.
// 8 phases, one __syncthreads each; P dbuf 48 KB -> 3 blocks/CU (12 waves).
// __launch_bounds__(256,3): min 3 waves/EU == what LDS allows anyway, so the
// VGPR cap rises to ~170 and the dbuf frag set (~150 live) does NOT spill
// (R13's failure mode: 512-thr shape squeezed to 64 VGPR and spilled).
__global__ void __launch_bounds__(256, 3) brc_fused(
    const f16* __restrict__ Af, const f16* __restrict__ Bf,
    const float* __restrict__ h0, const float* __restrict__ mr,
    const float* __restrict__ mz, const float* __restrict__ br,
    const float* __restrict__ bz, float* __restrict__ out) {
  __shared__ __align__(16) f16 Pl[2][12288];     // [buf][w*4096+tg*512+hl*8+t7]
  const int tid = threadIdx.x;
  const int wid = tid >> 6, lane = tid & 63;
  const int bid = blockIdx.x;
  const int lid = (bid & 7) * 128 + (bid >> 3);  // bijective XCD swizzle
  const int b = lid >> 3, hs = lid & 7;          // 8 hs-blocks of a b adjacent

  // ---- producer constants (waves 0..2): weight w3 = wid ----
  const int w3 = wid < 3 ? wid : 0;
  const char* Ap = (const char*)Af + lane * 16;
  const char* Bp = (const char*)Bf + (lane >> 4) * 1024 + (lane & 15) * 16 +
                   (size_t)(hs * 3 + w3) * 32768;
  const int col = lane & 15, rbase = (lane >> 4) * 4;

  // ---- consumer state (wave 3): chain = lane ----
  float h = 0.f, mrc = 0.f, mzc = 0.f, br2 = 0.f, nbz = 0.f;
  if (wid == 3) {
    int hg = hs * 64 + lane;
    h = h0[(size_t)b * 512 + hg];
    mrc = 2.0f * mr[hg]; mzc = -mz[hg];
    br2 = 2.0f * br[hg]; nbz = -bz[hg];
  }

#define LOADF(AA, BB, q, kt)                                                  \
  do {                                                                        \
    _Pragma("unroll") for (int mi = 0; mi < 4; ++mi)                          \
      AA[mi] = *(const f16x8*)(Ap +                                           \
                (size_t)((b * 32 + (q) * 4 + mi) * 8 + (kt)) * 1024);         \
    _Pragma("unroll") for (int ni = 0; ni < 4; ++ni)                          \
      BB[ni] = *(const f16x8*)(Bp + (size_t)(kt) * 4096 + ni * 256);          \
  } while (0)

#define MFMA16(AA, BB)                                                        \
  do {                                                                        \
    _Pragma("unroll") for (int mi = 0; mi < 4; ++mi)                          \
      _Pragma("unroll") for (int ni = 0; ni < 4; ++ni)                        \
        acc[mi][ni] = __builtin_amdgcn_mfma_f32_16x16x32_f16(                 \
            AA[mi], BB[ni], acc[mi][ni], 0, 0, 0);                            \
  } while (0)

  auto gemm_phase = [&](int q) {
    f16* Pb = Pl[q & 1];
    f32x4 acc[4][4] = {};
    f16x8 aE[4], bE[4], aO[4], bO[4];
    LOADF(aE, bE, q, 0);
#pragma unroll
    for (int kt = 0; kt < 8; kt += 2) {
      LOADF(aO, bO, q, kt + 1);                  // odd loads in flight
      __builtin_amdgcn_s_setprio(1);
      MFMA16(aE, bE);                            // even MFMAs cover them
      __builtin_amdgcn_s_setprio(0);
      if (kt + 2 < 8) LOADF(aE, bE, q, kt + 2);  // even loads in flight
      __builtin_amdgcn_s_setprio(1);
      MFMA16(aO, bO);
      __builtin_amdgcn_s_setprio(0);
    }
#pragma unroll
    for (int mi = 0; mi < 4; ++mi) {
      int tl = mi * 16 + rbase;                  // 0..63
#pragma unroll
      for (int ni = 0; ni < 4; ++ni) {
        int hl = ni * 16 + col;                  // 0..63
        f16x4 v;
#pragma unroll
        for (int r = 0; r < 4; ++r) v[r] = (f16)acc[mi][ni][r];
        *(f16x4*)&Pb[w3 * 4096 + (tl >> 3) * 512 + hl * 8 + (tl & 7)] = v;
      }
    }
  };

  if (wid < 3) gemm_phase(0);                    // prologue

  for (int p = 0; p < 8; ++p) {
    __syncthreads();                             // buf[p&1] ready; other free
    if (wid < 3) {
      if (p + 1 < 8) gemm_phase(p + 1);
    } else {
      const f16* Pb = Pl[p & 1];
      float* opm = out + ((size_t)b * 512 + p * 64) * 512 + hs * 64 + lane;
#pragma unroll
      for (int tg = 0; tg < 8; ++tg) {
        f16x8 R  = *(const f16x8*)&Pb[tg * 512 + lane * 8];
        f16x8 Z  = *(const f16x8*)&Pb[4096 + tg * 512 + lane * 8];
        f16x8 Hh = *(const f16x8*)&Pb[8192 + tg * 512 + lane * 8];
#pragma unroll
        for (int j = 0; j < 8; ++j) {
          float prs = fmaf((float)R[j], 2.0f, br2);
          float pzs = fmaf((float)Z[j], -1.0f, nbz);
          float ph2 = (float)Hh[j] * 2.0f;
          float er = __expf(fmaf(h, mrc, prs));
          float rr = fmaf(-2.0f, rcpf(er + 1.0f), 2.0f);
          float ez = __expf(fmaf(h, mzc, pzs));
          float zz = rcpf(1.0f + ez);
          float ec = __expf(fmaf(rr, h + h, ph2));
          float cd = fmaf(-2.0f, rcpf(ec + 1.0f), 1.0f);
          h = fmaf(zz, h - cd, cd);
          __builtin_nontemporal_store(h, opm + (size_t)(tg * 8 + j) * 512);
        }
      }
    }
  }
#undef LOADF
#undef MFMA16
}

// ---------------- launch ----------------
extern "C" void kernel_launch(void* const* d_in, const int* in_sizes, int n_in,
                              void* d_out, int out_size, void* d_ws, size_t ws_size,
                              hipStream_t stream) {
  const float* x  = (const float*)d_in[0];
  const float* h0 = (const float*)d_in[1];
  const float* kr = (const float*)d_in[2];
  const float* kz = (const float*)d_in[3];
  const float* kh = (const float*)d_in[4];
  const float* mr = (const float*)d_in[5];
  const float* mz = (const float*)d_in[6];
  const float* br = (const float*)d_in[7];
  const float* bz = (const float*)d_in[8];
  float* out = (float*)d_out;

  f16* Bf = (f16*)d_ws;                 // 393216 halfs = 786 KB
  f16* Xf = Bf + 393216;                // 16.8M halfs = 33.5 MB

  cvt_w<<<192, 256, 0, stream>>>(kr, kz, kh, Bf);
  cvt_x<<<8192, 256, 0, stream>>>(x, Xf);
  brc_fused<<<1024, 256, 0, stream>>>(Xf, Bf, h0, mr, mz, br, bz, out);
}

// Round 17
// 110.411 us; speedup vs baseline: 1.2142x; 1.2142x over previous
//
#include <hip/hip_runtime.h>

typedef _Float16 f16;
typedef _Float16 f16x8 __attribute__((ext_vector_type(8)));
typedef _Float16 f16x4 __attribute__((ext_vector_type(4)));
typedef float f32x4 __attribute__((ext_vector_type(4)));

__device__ __forceinline__ float rcpf(float x) { return __builtin_amdgcn_rcpf(x); }

__device__ __forceinline__ void gload_lds16(const void* g, void* l) {
  __builtin_amdgcn_global_load_lds(
      (const __attribute__((address_space(1))) void*)g,
      (__attribute__((address_space(3))) void*)l, 16, 0, 0);
}

// ---------------- kernel 1: weight convert -> FRAGMENT-ORDERED layout ------
// Wt'[(nt*3+w)*8+kt][kq][ni][rl][8 halfs]
__global__ void __launch_bounds__(256) cvt_w(const float* __restrict__ Wr,
                                             const float* __restrict__ Wz,
                                             const float* __restrict__ Wh,
                                             f16* __restrict__ out) {
  int o = blockIdx.x * 256 + threadIdx.x;        // < 49152
  int rl = o & 15, ni = (o >> 4) & 3, kq = (o >> 6) & 3, kt = (o >> 8) & 7;
  int wnt = o >> 11;
  int w = wnt % 3, nt = wnt / 3;
  int n = nt * 64 + ni * 16 + rl;
  int k0 = kt * 32 + kq * 8;
  const float* W = (w == 0) ? Wr : ((w == 1) ? Wz : Wh);
  f16x8 v;
#pragma unroll
  for (int e = 0; e < 8; ++e) v[e] = (f16)W[(size_t)(k0 + e) * 512 + n];
  *(f16x8*)(out + (size_t)o * 8) = v;
}

// ---------------- kernel 2: x convert f32->f16, FRAGMENT-ORDERED -----------
// Xf'[m16*8+kt][kq][rl][8 halfs]
__global__ void __launch_bounds__(256) cvt_x(const float* __restrict__ in,
                                             f16* __restrict__ out) {
  int o = blockIdx.x * 256 + threadIdx.x;        // < 2097152
  int rl = o & 15, kq = (o >> 4) & 3, kt = (o >> 6) & 7, m16 = o >> 9;
  const float* src = in + (size_t)(m16 * 16 + rl) * 256 + kt * 32 + kq * 8;
  f16x8 v;
#pragma unroll
  for (int e = 0; e < 8; ++e) v[e] = (f16)src[e];
  *(f16x8*)(out + (size_t)o * 8) = v;
}

// ---------------- kernel 3: producer/consumer fused GEMM + scan ------------
// R12 base (proven: 52 VGPR, no spill, fused=102us) + A-through-LDS:
// the 6 producer waves previously each loaded the SAME A frags from L1
// (6x redundant port bytes; A = 3MB/CU of the 9.2MB/CU port floor).
// Now each phase's A slice (16KB, contiguous in fragment order) is staged
// ONCE per block via global_load_lds; producers read it via ds_read_b128
// (LDS port, not L1 port). L1-port bytes/CU drop ~9.2 -> ~6.4 MB.
// LDS: P dbuf 48KB + A buf 16KB = 64KB -> 2 blocks/CU unchanged.
// Cost: one extra __syncthreads per phase (A-stage drain).
__global__ void __launch_bounds__(512, 4) brc_fused(
    const f16* __restrict__ Af, const f16* __restrict__ Bf,
    const float* __restrict__ h0, const float* __restrict__ mr,
    const float* __restrict__ mz, const float* __restrict__ br,
    const float* __restrict__ bz, float* __restrict__ out) {
  __shared__ __align__(16) f16 Pl[2][12288];     // [buf][w3*4096+tg*1024+hl*8+t7]
  __shared__ __align__(16) f16 Al[8192];         // 16KB: phase A slice, frag order
  const int tid = threadIdx.x;
  const int wid = tid >> 6, lane = tid & 63;
  const int bid = blockIdx.x;
  const int lid = (bid & 7) * 64 + (bid >> 3);   // bijective XCD swizzle
  const int b = lid >> 2, hs = lid & 3;          // 4 hs-blocks of a b adjacent

  // ---- producer constants (waves 0..5) ----
  const int w3 = wid >> 1, hh = wid & 1;
  const int nt = hs * 2 + hh;
  const char* Bp = (const char*)Bf + (lane >> 4) * 1024 + (lane & 15) * 16 +
                   (size_t)(nt * 3 + w3) * 32768;
  const int col = lane & 15, rbase = (lane >> 4) * 4;

  // ---- consumer state (waves 6,7): chain c = tid & 127 ----
  const int c = tid & 127;
  const int hg = hs * 128 + c;
  float h = h0[(size_t)b * 512 + hg];
  const float mrc = 2.0f * mr[hg], mzc = -mz[hg];
  const float br2 = 2.0f * br[hg], nbz = -bz[hg];

  // stage phase q's A slice: 16 contiguous 1KB chunks, 6 waves round-robin.
  // global frag (q*2+mi)*8+kt -> chunk j = mi*8+kt, contiguous 16KB region.
#define STAGEA(q)                                                             \
  do {                                                                        \
    const char* gsrc = (const char*)Af + ((size_t)(b * 32 + (q) * 2) * 8) * 1024; \
    for (int j = wid; j < 16; j += 6)                                         \
      gload_lds16(gsrc + (size_t)j * 1024 + lane * 16, (char*)Al + j * 1024); \
  } while (0)

  auto gemm_phase = [&](int q) {
    f16* Pb = Pl[q & 1];
    f32x4 acc[2][4] = {};
#pragma unroll
    for (int kt = 0; kt < 8; ++kt) {
      f16x8 a[2], bfr[4];
#pragma unroll
      for (int mi = 0; mi < 2; ++mi)
        a[mi] = *(const f16x8*)((const char*)Al + (mi * 8 + kt) * 1024 + lane * 16);
#pragma unroll
      for (int ni = 0; ni < 4; ++ni)
        bfr[ni] = *(const f16x8*)(Bp + (size_t)kt * 4096 + ni * 256);
#pragma unroll
      for (int mi = 0; mi < 2; ++mi)
#pragma unroll
        for (int ni = 0; ni < 4; ++ni)
          acc[mi][ni] = __builtin_amdgcn_mfma_f32_16x16x32_f16(
              a[mi], bfr[ni], acc[mi][ni], 0, 0, 0);
    }
#pragma unroll
    for (int mi = 0; mi < 2; ++mi) {
      int tl = mi * 16 + rbase;                  // 0..31
#pragma unroll
      for (int ni = 0; ni < 4; ++ni) {
        int hl = hh * 64 + ni * 16 + col;        // 0..127
        f16x4 v;
#pragma unroll
        for (int r = 0; r < 4; ++r) v[r] = (f16)acc[mi][ni][r];
        *(f16x4*)&Pb[w3 * 4096 + (tl >> 3) * 1024 + hl * 8 + (tl & 7)] = v;
      }
    }
  };

  if (wid < 6) STAGEA(0);
  __syncthreads();                               // A0 landed (vmcnt drain)
  if (wid < 6) gemm_phase(0);                    // prologue

  for (int p = 0; p < 16; ++p) {
    __syncthreads();                             // P[p&1] ready; A[p] dead
    if (wid < 6 && p + 1 < 16) STAGEA(p + 1);
    __syncthreads();                             // A[p+1] landed
    if (wid < 6) {
      if (p + 1 < 16) gemm_phase(p + 1);
    } else {
      const f16* Pr_ = &Pl[p & 1][c * 8];
      const f16* Pz_ = Pr_ + 4096;
      const f16* Ph_ = Pr_ + 8192;
      float* opm = out + ((size_t)b * 512 + p * 32) * 512 + hg;
#pragma unroll
      for (int g = 0; g < 4; ++g) {
        f16x8 R  = *(const f16x8*)(Pr_ + g * 1024);
        f16x8 Z  = *(const f16x8*)(Pz_ + g * 1024);
        f16x8 Hh = *(const f16x8*)(Ph_ + g * 1024);
#pragma unroll
        for (int j = 0; j < 8; ++j) {
          float prs = fmaf((float)R[j], 2.0f, br2);
          float pzs = fmaf((float)Z[j], -1.0f, nbz);
          float ph2 = (float)Hh[j] * 2.0f;
          float er = __expf(fmaf(h, mrc, prs));
          float rr = fmaf(-2.0f, rcpf(er + 1.0f), 2.0f);
          float ez = __expf(fmaf(h, mzc, pzs));
          float zz = rcpf(1.0f + ez);
          float ec = __expf(fmaf(rr, h + h, ph2));
          float cd = fmaf(-2.0f, rcpf(ec + 1.0f), 1.0f);
          h = fmaf(zz, h - cd, cd);
          __builtin_nontemporal_store(h, opm + (size_t)(g * 8 + j) * 512);
        }
      }
    }
  }
#undef STAGEA
}

// ---------------- launch ----------------
extern "C" void kernel_launch(void* const* d_in, const int* in_sizes, int n_in,
                              void* d_out, int out_size, void* d_ws, size_t ws_size,
                              hipStream_t stream) {
  const float* x  = (const float*)d_in[0];
  const float* h0 = (const float*)d_in[1];
  const float* kr = (const float*)d_in[2];
  const float* kz = (const float*)d_in[3];
  const float* kh = (const float*)d_in[4];
  const float* mr = (const float*)d_in[5];
  const float* mz = (const float*)d_in[6];
  const float* br = (const float*)d_in[7];
  const float* bz = (const float*)d_in[8];
  float* out = (float*)d_out;

  f16* Bf = (f16*)d_ws;                 // 393216 halfs = 786 KB
  f16* Xf = Bf + 393216;                // 16.8M halfs = 33.5 MB

  cvt_w<<<192, 256, 0, stream>>>(kr, kz, kh, Bf);
  cvt_x<<<8192, 256, 0, stream>>>(x, Xf);
  brc_fused<<<512, 512, 0, stream>>>(Xf, Bf, h0, mr, mz, br, bz, out);
}